// Round 1
// baseline (2599.108 us; speedup 1.0000x reference)
//
#include <hip/hip_runtime.h>
#include <math.h>

// Problem constants (fixed by setup_inputs)
constexpr int B_ = 8192;   // batch rows
constexpr int D_ = 1024;   // per-expert feature dim
constexpr int M_ = 8;      // experts
constexpr int H_ = 256;    // gate hidden dim
constexpr int KTOT = M_ * D_;   // 8192 = GEMM1 K

// GEMM1 tiling
constexpr int SPLITK = 4;
constexpr int KSP = KTOT / SPLITK;   // 2048 (spans exactly 2 experts; BK chunks never straddle an m-boundary since 1024 % 16 == 0)
constexpr int BM = 128, BN = 128, BK = 16;
constexpr int NCH = KSP / BK;        // 128 K-chunks per block

// ---------------------------------------------------------------------------
// Kernel 1: partial[s] = cat[:, sK:(s+1)K] @ W1[sK:(s+1)K, :]   (fp32, no bias)
// cat[b, k] = zs[k>>10, b, k&1023]
// ---------------------------------------------------------------------------
__global__ __launch_bounds__(256, 2)
void gemm1_kernel(const float* __restrict__ zs, const float* __restrict__ W1,
                  float* __restrict__ part)
{
    __shared__ float As[2][BK][BM + 4];   // [buf][k][m], +4 pad keeps 16B align & kills write conflicts
    __shared__ float Bs[2][BK * BN];      // [buf][k*BN + n], lane-contiguous writes -> conflict-free

    const int t  = threadIdx.x;
    const int tx = t & 15;        // output col group (8 cols: tx*4 and tx*4+64)
    const int ty = t >> 4;        // output row group (8 rows: ty*8..+7)
    const int c0 = blockIdx.x * BN;       // 0 or 128
    const int b0 = blockIdx.y * BM;       // row block
    const int s  = blockIdx.z;            // split-K index
    const int k0 = s * KSP;

    // A staging: thread loads float4 at (row=ar0, k=akq..akq+3) and (row=ar0+64, same k)
    const int ar0 = t >> 2;               // 0..63
    const int akq = (t & 3) << 2;         // 0,4,8,12

    float acc[8][8];
#pragma unroll
    for (int i = 0; i < 8; ++i)
#pragma unroll
        for (int j = 0; j < 8; ++j) acc[i][j] = 0.f;

    float4 ra0, ra1, rb0, rb1;

    auto load_chunk = [&](int ch) {
        const int kg = k0 + ch * BK;
        const int m  = kg >> 10;
        const int dd = (kg & 1023) + akq;
        const float* pz = zs + ((size_t)m * B_ + b0) * D_ + dd;
        ra0 = *(const float4*)(pz + (size_t)ar0 * D_);
        ra1 = *(const float4*)(pz + (size_t)(ar0 + 64) * D_);
        // B: lane-contiguous sweep of the 16x128 tile (row kk = t>>5 and +8)
        const float* pw = W1 + (size_t)kg * H_ + c0 + ((t & 31) << 2);
        rb0 = *(const float4*)(pw + (size_t)(t >> 5) * H_);
        rb1 = *(const float4*)(pw + (size_t)((t >> 5) + 8) * H_);
    };
    auto store_chunk = [&](int buf) {
        const float* a0 = (const float*)&ra0;
        const float* a1 = (const float*)&ra1;
#pragma unroll
        for (int j = 0; j < 4; ++j) {
            As[buf][akq + j][ar0]      = a0[j];
            As[buf][akq + j][ar0 + 64] = a1[j];
        }
        *(float4*)&Bs[buf][t * 4]        = rb0;   // flat = (t>>5)*128 + (t&31)*4 = 4t
        *(float4*)&Bs[buf][t * 4 + 1024] = rb1;
    };

    load_chunk(0);
    store_chunk(0);
    __syncthreads();

    for (int ch = 0; ch < NCH; ++ch) {
        const int cur = ch & 1;
        if (ch + 1 < NCH) load_chunk(ch + 1);

#pragma unroll
        for (int kk = 0; kk < BK; ++kk) {
            const float4 a0 = *(const float4*)&As[cur][kk][ty * 8];
            const float4 a1 = *(const float4*)&As[cur][kk][ty * 8 + 4];
            const float4 v0 = *(const float4*)&Bs[cur][kk * BN + tx * 4];
            const float4 v1 = *(const float4*)&Bs[cur][kk * BN + tx * 4 + 64];
            const float a[8]  = {a0.x, a0.y, a0.z, a0.w, a1.x, a1.y, a1.z, a1.w};
            const float bv[8] = {v0.x, v0.y, v0.z, v0.w, v1.x, v1.y, v1.z, v1.w};
#pragma unroll
            for (int i = 0; i < 8; ++i)
#pragma unroll
                for (int j = 0; j < 8; ++j)
                    acc[i][j] = fmaf(a[i], bv[j], acc[i][j]);
        }

        if (ch + 1 < NCH) {
            store_chunk(cur ^ 1);
            __syncthreads();
        }
    }

    // Epilogue: write fp32 partial (bias/GELU applied in gate kernel)
    float* P = part + (size_t)s * (B_ * H_) + (size_t)(b0 + ty * 8) * H_ + c0;
#pragma unroll
    for (int i = 0; i < 8; ++i) {
        float4 o0 = make_float4(acc[i][0], acc[i][1], acc[i][2], acc[i][3]);
        float4 o1 = make_float4(acc[i][4], acc[i][5], acc[i][6], acc[i][7]);
        *(float4*)(P + (size_t)i * H_ + tx * 4)      = o0;
        *(float4*)(P + (size_t)i * H_ + tx * 4 + 64) = o1;
    }
}

// ---------------------------------------------------------------------------
// Kernel 2: h = gelu(sum(partials) + b1); logits = h@W2 + b2; top-2 softmax;
// write dense w to d_out; write (idx, weight) pairs to ws for combine.
// ---------------------------------------------------------------------------
__device__ __forceinline__ float gelu_exact(float x) {
    return 0.5f * x * (1.0f + erff(x * 0.70710678118654752f));
}

__global__ __launch_bounds__(256)
void gate_kernel(const float* __restrict__ part, const float* __restrict__ b1,
                 const float* __restrict__ W2, const float* __restrict__ b2,
                 float* __restrict__ w_out, int2* __restrict__ sel,
                 float2* __restrict__ wt)
{
    __shared__ float W2s[H_ * M_];   // 2048
    __shared__ float b1s[H_];
    __shared__ float red[32][8][8];  // [row][li][expert]

    const int t = threadIdx.x;
#pragma unroll
    for (int q = 0; q < 8; ++q) W2s[t + q * 256] = W2[t + q * 256];
    b1s[t] = b1[t];
    __syncthreads();

    const int r  = t >> 3;   // 0..31 local row
    const int li = t & 7;    // 0..7  H-slice
    const int b  = blockIdx.x * 32 + r;

    const float* p0 = part + (size_t)b * H_;
    const float* p1 = p0 + (size_t)B_ * H_;
    const float* p2 = p1 + (size_t)B_ * H_;
    const float* p3 = p2 + (size_t)B_ * H_;

    float lg[8] = {0, 0, 0, 0, 0, 0, 0, 0};
#pragma unroll
    for (int jj = 0; jj < 8; ++jj) {
        const int j = li * 32 + jj * 4;
        const float4 q0 = *(const float4*)(p0 + j);
        const float4 q1 = *(const float4*)(p1 + j);
        const float4 q2 = *(const float4*)(p2 + j);
        const float4 q3 = *(const float4*)(p3 + j);
        const float xs[4] = {q0.x + q1.x + q2.x + q3.x,
                             q0.y + q1.y + q2.y + q3.y,
                             q0.z + q1.z + q2.z + q3.z,
                             q0.w + q1.w + q2.w + q3.w};
#pragma unroll
        for (int u = 0; u < 4; ++u) {
            const float h = gelu_exact(xs[u] + b1s[j + u]);
#pragma unroll
            for (int i = 0; i < 8; ++i)
                lg[i] = fmaf(h, W2s[(j + u) * 8 + i], lg[i]);
        }
    }
#pragma unroll
    for (int i = 0; i < 8; ++i) red[r][li][i] = lg[i];
    __syncthreads();

    if (t < 32) {
        const int bb = blockIdx.x * 32 + t;
        float l[8];
#pragma unroll
        for (int i = 0; i < 8; ++i) {
            float v = b2[i];
#pragma unroll
            for (int q = 0; q < 8; ++q) v += red[t][q][i];
            l[i] = v;
        }
        // top-2 (strict > keeps lowest index on ties, matching lax.top_k)
        int i1 = 0; float l1 = l[0];
#pragma unroll
        for (int i = 1; i < 8; ++i) if (l[i] > l1) { l1 = l[i]; i1 = i; }
        int i2 = (i1 == 0) ? 1 : 0; float l2 = l[i2];
#pragma unroll
        for (int i = 0; i < 8; ++i)
            if (i != i1 && l[i] > l2) { l2 = l[i]; i2 = i; }

        const float e  = expf(l2 - l1);      // l1 >= l2, stable
        const float dn = 1.0f + e;
        const float wa = 1.0f / dn;
        const float wb = e / dn;

        float* wr = w_out + (size_t)bb * M_;
#pragma unroll
        for (int i = 0; i < 8; ++i) wr[i] = 0.f;
        wr[i1] = wa;
        wr[i2] = wb;
        sel[bb] = make_int2(i1, i2);
        wt[bb]  = make_float2(wa, wb);
    }
}

// ---------------------------------------------------------------------------
// Kernel 3: fused[b,:] = wa*zs[e1,b,:] + wb*zs[e2,b,:]
// ---------------------------------------------------------------------------
__global__ __launch_bounds__(256)
void combine_kernel(const float* __restrict__ zs, const int2* __restrict__ sel,
                    const float2* __restrict__ wt, float* __restrict__ fused)
{
    const int b = blockIdx.x;
    const int2  e = sel[b];
    const float2 w = wt[b];
    const float4* z1 = (const float4*)(zs + ((size_t)e.x * B_ + b) * D_);
    const float4* z2 = (const float4*)(zs + ((size_t)e.y * B_ + b) * D_);
    float4* o = (float4*)(fused + (size_t)b * D_);
    const int d = threadIdx.x;           // 256 threads * float4 = 1024
    const float4 x = z1[d];
    const float4 y = z2[d];
    o[d] = make_float4(fmaf(w.x, x.x, w.y * y.x),
                       fmaf(w.x, x.y, w.y * y.y),
                       fmaf(w.x, x.z, w.y * y.z),
                       fmaf(w.x, x.w, w.y * y.w));
}

// ---------------------------------------------------------------------------
extern "C" void kernel_launch(void* const* d_in, const int* in_sizes, int n_in,
                              void* d_out, int out_size, void* d_ws, size_t ws_size,
                              hipStream_t stream)
{
    const float* zs = (const float*)d_in[0];
    const float* W1 = (const float*)d_in[1];
    const float* b1 = (const float*)d_in[2];
    const float* W2 = (const float*)d_in[3];
    const float* b2 = (const float*)d_in[4];

    float* fused = (float*)d_out;                       // [8192][1024]
    float* w_out = fused + (size_t)B_ * D_;             // [8192][8]

    // ws layout: partials [SPLITK][B][H] fp32 (32 MB) | sel int2[B] | wt float2[B]
    float*  part = (float*)d_ws;
    int2*   sel  = (int2*)(part + (size_t)SPLITK * B_ * H_);
    float2* wt   = (float2*)(sel + B_);

    gemm1_kernel<<<dim3(BN == 128 ? 2 : H_ / BN, B_ / BM, SPLITK), 256, 0, stream>>>(zs, W1, part);
    gate_kernel<<<dim3(B_ / 32), 256, 0, stream>>>(part, b1, W2, b2, w_out, sel, wt);
    combine_kernel<<<dim3(B_), 256, 0, stream>>>(zs, sel, wt, fused);
}

// Round 2
// 733.618 us; speedup vs baseline: 3.5429x; 3.5429x over previous
//
#include <hip/hip_runtime.h>
#include <math.h>

// Problem constants (fixed by setup_inputs)
constexpr int B_ = 8192;   // batch rows
constexpr int D_ = 1024;   // per-expert feature dim
constexpr int M_ = 8;      // experts
constexpr int H_ = 256;    // gate hidden dim
constexpr int KTOT = M_ * D_;   // 8192 = GEMM1 K

// GEMM1 tiling
constexpr int SPLITK = 4;
constexpr int KSP = KTOT / SPLITK;   // 2048 (BK chunks never straddle an expert boundary: 1024 % 16 == 0)
constexpr int BM = 64, BN = 128, BK = 16;
constexpr int NCH = KSP / BK;        // 128 K-chunks per block

// ---------------------------------------------------------------------------
// Kernel 1: partial[s] = cat[:, sK:(s+1)K] @ W1[sK:(s+1)K, :]   (fp32, no bias)
// cat[b, k] = zs[k>>10, b, k&1023]
// Spill-proof rules: no lambdas, no local temp arrays, constant indices only.
// ---------------------------------------------------------------------------
__global__ __launch_bounds__(256, 4)
void gemm1_kernel(const float* __restrict__ zs, const float* __restrict__ W1,
                  float* __restrict__ part)
{
    __shared__ float As[2][BK][BM + 4];   // 8704 B  [buf][k][m], +4 pad
    __shared__ float Bs[2][BK][BN];       // 16384 B [buf][k][n], lane-contiguous writes

    const int t  = threadIdx.x;
    const int tx = t & 15;        // output col group: cols tx*4..+3 and +64
    const int ty = t >> 4;        // output row group: rows ty*4..+3
    const int c0 = blockIdx.x * BN;
    const int b0 = blockIdx.y * BM;
    const int k0 = blockIdx.z * KSP;

    // A staging: thread t loads float4 at (row = t>>2, k-offset = (t&3)*4)
    const int ar = t >> 2;               // 0..63
    const int ak = (t & 3) << 2;         // 0,4,8,12
    // B staging: thread t loads rows (t>>5) and (t>>5)+8, col (t&31)*4
    const int br = t >> 5;               // 0..7
    const int bc = (t & 31) << 2;        // 0..124

    float acc[4][8];
#pragma unroll
    for (int i = 0; i < 4; ++i)
#pragma unroll
        for (int j = 0; j < 8; ++j) acc[i][j] = 0.f;

    float4 ra, rb0, rb1;

    // ---- prologue: load + store chunk 0 into buf 0 ----
    {
        const int kg = k0;
        const float* pz = zs + ((size_t)(kg >> 10) * B_ + b0 + ar) * D_ + (kg & 1023) + ak;
        ra = *(const float4*)pz;
        const float* pw = W1 + (size_t)(kg + br) * H_ + c0 + bc;
        rb0 = *(const float4*)pw;
        rb1 = *(const float4*)(pw + (size_t)8 * H_);
    }
    As[0][ak + 0][ar] = ra.x;
    As[0][ak + 1][ar] = ra.y;
    As[0][ak + 2][ar] = ra.z;
    As[0][ak + 3][ar] = ra.w;
    *(float4*)&Bs[0][br][bc]     = rb0;
    *(float4*)&Bs[0][br + 8][bc] = rb1;
    __syncthreads();

    for (int ch = 0; ch < NCH; ++ch) {
        const int cur = ch & 1;

        if (ch + 1 < NCH) {
            const int kg = k0 + (ch + 1) * BK;
            const float* pz = zs + ((size_t)(kg >> 10) * B_ + b0 + ar) * D_ + (kg & 1023) + ak;
            ra = *(const float4*)pz;
            const float* pw = W1 + (size_t)(kg + br) * H_ + c0 + bc;
            rb0 = *(const float4*)pw;
            rb1 = *(const float4*)(pw + (size_t)8 * H_);
        }

#pragma unroll
        for (int kk = 0; kk < BK; ++kk) {
            const float4 a = *(const float4*)&As[cur][kk][ty * 4];
            const float4 p = *(const float4*)&Bs[cur][kk][tx * 4];
            const float4 q = *(const float4*)&Bs[cur][kk][tx * 4 + 64];
#define MOE_ROW(i, ai)                                                         \
            acc[i][0] = fmaf(ai, p.x, acc[i][0]);                              \
            acc[i][1] = fmaf(ai, p.y, acc[i][1]);                              \
            acc[i][2] = fmaf(ai, p.z, acc[i][2]);                              \
            acc[i][3] = fmaf(ai, p.w, acc[i][3]);                              \
            acc[i][4] = fmaf(ai, q.x, acc[i][4]);                              \
            acc[i][5] = fmaf(ai, q.y, acc[i][5]);                              \
            acc[i][6] = fmaf(ai, q.z, acc[i][6]);                              \
            acc[i][7] = fmaf(ai, q.w, acc[i][7]);
            MOE_ROW(0, a.x)
            MOE_ROW(1, a.y)
            MOE_ROW(2, a.z)
            MOE_ROW(3, a.w)
#undef MOE_ROW
        }

        if (ch + 1 < NCH) {
            const int nxt = cur ^ 1;
            As[nxt][ak + 0][ar] = ra.x;
            As[nxt][ak + 1][ar] = ra.y;
            As[nxt][ak + 2][ar] = ra.z;
            As[nxt][ak + 3][ar] = ra.w;
            *(float4*)&Bs[nxt][br][bc]     = rb0;
            *(float4*)&Bs[nxt][br + 8][bc] = rb1;
            __syncthreads();
        }
    }

    // Epilogue: write fp32 partial (bias/GELU applied in gate kernel)
    float* P = part + (size_t)blockIdx.z * (B_ * H_) + (size_t)(b0 + ty * 4) * H_ + c0;
#pragma unroll
    for (int i = 0; i < 4; ++i) {
        float4 o0 = make_float4(acc[i][0], acc[i][1], acc[i][2], acc[i][3]);
        float4 o1 = make_float4(acc[i][4], acc[i][5], acc[i][6], acc[i][7]);
        *(float4*)(P + (size_t)i * H_ + tx * 4)      = o0;
        *(float4*)(P + (size_t)i * H_ + tx * 4 + 64) = o1;
    }
}

// ---------------------------------------------------------------------------
// Kernel 2: h = gelu(sum(partials) + b1); logits = h@W2 + b2; top-2 softmax;
// write dense w to d_out; write (idx, weight) pairs to ws for combine.
// ---------------------------------------------------------------------------
__device__ __forceinline__ float gelu_exact(float x) {
    return 0.5f * x * (1.0f + erff(x * 0.70710678118654752f));
}

__global__ __launch_bounds__(256)
void gate_kernel(const float* __restrict__ part, const float* __restrict__ b1,
                 const float* __restrict__ W2, const float* __restrict__ b2,
                 float* __restrict__ w_out, int2* __restrict__ sel,
                 float2* __restrict__ wt)
{
    __shared__ float W2s[H_ * M_];   // 2048
    __shared__ float b1s[H_];
    __shared__ float red[32][8][8];  // [row][li][expert]

    const int t = threadIdx.x;
#pragma unroll
    for (int q = 0; q < 8; ++q) W2s[t + q * 256] = W2[t + q * 256];
    b1s[t] = b1[t];
    __syncthreads();

    const int r  = t >> 3;   // 0..31 local row
    const int li = t & 7;    // 0..7  H-slice
    const int b  = blockIdx.x * 32 + r;

    const float* p0 = part + (size_t)b * H_;
    const float* p1 = p0 + (size_t)B_ * H_;
    const float* p2 = p1 + (size_t)B_ * H_;
    const float* p3 = p2 + (size_t)B_ * H_;

    float lg[8] = {0, 0, 0, 0, 0, 0, 0, 0};
#pragma unroll
    for (int jj = 0; jj < 8; ++jj) {
        const int j = li * 32 + jj * 4;
        const float4 q0 = *(const float4*)(p0 + j);
        const float4 q1 = *(const float4*)(p1 + j);
        const float4 q2 = *(const float4*)(p2 + j);
        const float4 q3 = *(const float4*)(p3 + j);
        const float x0 = q0.x + q1.x + q2.x + q3.x;
        const float x1 = q0.y + q1.y + q2.y + q3.y;
        const float x2 = q0.z + q1.z + q2.z + q3.z;
        const float x3 = q0.w + q1.w + q2.w + q3.w;
        const float h0 = gelu_exact(x0 + b1s[j + 0]);
        const float h1 = gelu_exact(x1 + b1s[j + 1]);
        const float h2 = gelu_exact(x2 + b1s[j + 2]);
        const float h3 = gelu_exact(x3 + b1s[j + 3]);
#pragma unroll
        for (int i = 0; i < 8; ++i) {
            lg[i] = fmaf(h0, W2s[(j + 0) * 8 + i], lg[i]);
            lg[i] = fmaf(h1, W2s[(j + 1) * 8 + i], lg[i]);
            lg[i] = fmaf(h2, W2s[(j + 2) * 8 + i], lg[i]);
            lg[i] = fmaf(h3, W2s[(j + 3) * 8 + i], lg[i]);
        }
    }
#pragma unroll
    for (int i = 0; i < 8; ++i) red[r][li][i] = lg[i];
    __syncthreads();

    if (t < 32) {
        const int bb = blockIdx.x * 32 + t;
        float l[8];
#pragma unroll
        for (int i = 0; i < 8; ++i) {
            float v = b2[i];
#pragma unroll
            for (int q = 0; q < 8; ++q) v += red[t][q][i];
            l[i] = v;
        }
        // top-2 (strict > keeps lowest index on ties, matching lax.top_k)
        int i1 = 0; float l1 = l[0];
#pragma unroll
        for (int i = 1; i < 8; ++i) if (l[i] > l1) { l1 = l[i]; i1 = i; }
        int i2 = (i1 == 0) ? 1 : 0; float l2 = l[i2];
#pragma unroll
        for (int i = 0; i < 8; ++i)
            if (i != i1 && l[i] > l2) { l2 = l[i]; i2 = i; }

        const float e  = expf(l2 - l1);      // l1 >= l2, stable
        const float dn = 1.0f + e;
        const float wa = 1.0f / dn;
        const float wb = e / dn;

        float* wr = w_out + (size_t)bb * M_;
#pragma unroll
        for (int i = 0; i < 8; ++i) wr[i] = 0.f;
        wr[i1] = wa;
        wr[i2] = wb;
        sel[bb] = make_int2(i1, i2);
        wt[bb]  = make_float2(wa, wb);
    }
}

// ---------------------------------------------------------------------------
// Kernel 3: fused[b,:] = wa*zs[e1,b,:] + wb*zs[e2,b,:]
// ---------------------------------------------------------------------------
__global__ __launch_bounds__(256)
void combine_kernel(const float* __restrict__ zs, const int2* __restrict__ sel,
                    const float2* __restrict__ wt, float* __restrict__ fused)
{
    const int b = blockIdx.x;
    const int2  e = sel[b];
    const float2 w = wt[b];
    const float4* z1 = (const float4*)(zs + ((size_t)e.x * B_ + b) * D_);
    const float4* z2 = (const float4*)(zs + ((size_t)e.y * B_ + b) * D_);
    float4* o = (float4*)(fused + (size_t)b * D_);
    const int d = threadIdx.x;           // 256 threads * float4 = 1024
    const float4 x = z1[d];
    const float4 y = z2[d];
    o[d] = make_float4(fmaf(w.x, x.x, w.y * y.x),
                       fmaf(w.x, x.y, w.y * y.y),
                       fmaf(w.x, x.z, w.y * y.z),
                       fmaf(w.x, x.w, w.y * y.w));
}

// ---------------------------------------------------------------------------
extern "C" void kernel_launch(void* const* d_in, const int* in_sizes, int n_in,
                              void* d_out, int out_size, void* d_ws, size_t ws_size,
                              hipStream_t stream)
{
    const float* zs = (const float*)d_in[0];
    const float* W1 = (const float*)d_in[1];
    const float* b1 = (const float*)d_in[2];
    const float* W2 = (const float*)d_in[3];
    const float* b2 = (const float*)d_in[4];

    float* fused = (float*)d_out;                       // [8192][1024]
    float* w_out = fused + (size_t)B_ * D_;             // [8192][8]

    // ws layout: partials [SPLITK][B][H] fp32 (32 MB) | sel int2[B] | wt float2[B]
    float*  part = (float*)d_ws;
    int2*   sel  = (int2*)(part + (size_t)SPLITK * B_ * H_);
    float2* wt   = (float2*)(sel + B_);

    gemm1_kernel<<<dim3(H_ / BN, B_ / BM, SPLITK), 256, 0, stream>>>(zs, W1, part);
    gate_kernel<<<dim3(B_ / 32), 256, 0, stream>>>(part, b1, W2, b2, w_out, sel, wt);
    combine_kernel<<<dim3(B_), 256, 0, stream>>>(zs, sel, wt, fused);
}

// Round 3
// 545.139 us; speedup vs baseline: 4.7678x; 1.3457x over previous
//
#include <hip/hip_runtime.h>
#include <math.h>

// Problem constants
constexpr int B_ = 8192;   // batch rows
constexpr int D_ = 1024;   // per-expert dim
constexpr int M_ = 8;      // experts
constexpr int H_ = 256;    // gate hidden
// GEMM1: cat[8192 x 8192] @ W1[8192 x 256], fp32 via bf16-triple MFMA emulation
constexpr int SPLITK = 4;
constexpr int KSP = 2048;          // K per split (16-chunks never straddle expert boundary)
constexpr int BM = 128, BN = 256, BK = 16;
constexpr int NCH = KSP / BK;      // 128 chunks

typedef __bf16 bf16x8 __attribute__((ext_vector_type(8)));
typedef float  f32x16 __attribute__((ext_vector_type(16)));
typedef short  short8 __attribute__((ext_vector_type(8)));

__device__ __forceinline__ unsigned short f2bf(float x) {
    unsigned int u = __float_as_uint(x);
    u += 0x7FFFu + ((u >> 16) & 1u);           // round-to-nearest-even
    return (unsigned short)(u >> 16);
}
__device__ __forceinline__ float bf2f(unsigned short s) {
    return __uint_as_float(((unsigned int)s) << 16);
}

#define MFMA(A, Bf, C) __builtin_amdgcn_mfma_f32_32x32x16_bf16((A), (Bf), (C), 0, 0, 0)

// ---------------------------------------------------------------------------
// GEMM1: part[s] = cat[:, sK:(s+1)K] @ W1[sK:(s+1)K, :]
// cat[b,k] = zs[k>>10, b, k&1023].  fp32 emulated as 6 bf16 MFMA passes:
// x = h + m + l (bf16 each); keep hh, hm, mh, mm, hl, lh (drop <= 2^-27 terms).
// LDS: 16B "chunks" fragment-contiguous; consecutive lanes read consecutive
// chunks -> conflict-free ds_read_b128. A-store XOR-swizzled (2-way max).
// ---------------------------------------------------------------------------
__global__ __launch_bounds__(256, 1)
void gemm1_kernel(const float* __restrict__ zs, const float* __restrict__ W1,
                  float* __restrict__ part)
{
    // chunk(ks, m): holds 8 bf16 (k = ks*8..+7) for row m. idx = ks*128 + (m^ks)
    __shared__ short Ah[2 * 128 * 8], Am_[2 * 128 * 8], Al[2 * 128 * 8];  // 4 KB each
    // chunk(ks, n): idx = ks*256 + n
    __shared__ short Bh[2 * 256 * 8], Bm_[2 * 256 * 8], Bl[2 * 256 * 8];  // 8 KB each

    const int t  = threadIdx.x;
    const int b0 = blockIdx.x * BM;
    const int s  = blockIdx.y;
    const int k0 = s * KSP;

    // A staging: thread t -> row amr = t>>1 (0..127), k-offset 8*(t&1)
    const int amr = t >> 1;
    const int aks = t & 1;

    const int lane = t & 63;
    const int wv   = t >> 6;        // wave 0..3 -> cols wv*64..+63
    const int kl   = lane >> 5;     // k-half 0/1
    const int ln   = lane & 31;

    f32x16 acc[8];
#pragma unroll
    for (int i = 0; i < 8; ++i) acc[i] = (f32x16)0.0f;

    float4 a0, a1;
    float  bv[16];

#define LOAD_REGS(KG) {                                                        \
    const int kgv = (KG);                                                      \
    const float* pz = zs + ((size_t)(kgv >> 10) * B_ + b0 + amr) * D_          \
                         + (kgv & 1023) + aks * 8;                             \
    a0 = *(const float4*)pz;                                                   \
    a1 = *(const float4*)(pz + 4);                                             \
    const float* pw = W1 + (size_t)kgv * H_ + t;                               \
    _Pragma("unroll")                                                          \
    for (int k2 = 0; k2 < 16; ++k2) bv[k2] = pw[k2 * H_];                      \
}

#define SPLIT_STORE() {                                                        \
    float av[8] = {a0.x, a0.y, a0.z, a0.w, a1.x, a1.y, a1.z, a1.w};            \
    short8 vh, vm, vl;                                                         \
    _Pragma("unroll")                                                          \
    for (int j = 0; j < 8; ++j) {                                              \
        unsigned short h = f2bf(av[j]);                                        \
        float r = av[j] - bf2f(h);                                             \
        unsigned short mm = f2bf(r);                                           \
        r = r - bf2f(mm);                                                      \
        unsigned short ll = f2bf(r);                                           \
        vh[j] = (short)h; vm[j] = (short)mm; vl[j] = (short)ll;                \
    }                                                                          \
    const int ia = aks * 128 + (amr ^ aks);                                    \
    *(short8*)&Ah[ia * 8]  = vh;                                               \
    *(short8*)&Am_[ia * 8] = vm;                                               \
    *(short8*)&Al[ia * 8]  = vl;                                               \
    _Pragma("unroll")                                                          \
    for (int ks = 0; ks < 2; ++ks) {                                           \
        short8 wh, wm, wl;                                                     \
        _Pragma("unroll")                                                      \
        for (int j = 0; j < 8; ++j) {                                          \
            unsigned short h = f2bf(bv[ks * 8 + j]);                           \
            float r = bv[ks * 8 + j] - bf2f(h);                                \
            unsigned short mm = f2bf(r);                                       \
            r = r - bf2f(mm);                                                  \
            unsigned short ll = f2bf(r);                                       \
            wh[j] = (short)h; wm[j] = (short)mm; wl[j] = (short)ll;            \
        }                                                                      \
        const int ib = ks * 256 + t;                                           \
        *(short8*)&Bh[ib * 8]  = wh;                                           \
        *(short8*)&Bm_[ib * 8] = wm;                                           \
        *(short8*)&Bl[ib * 8]  = wl;                                           \
    }                                                                          \
}

    LOAD_REGS(k0)
    SPLIT_STORE()
    __syncthreads();

#pragma unroll 1
    for (int c = 0; c < NCH; ++c) {
        if (c + 1 < NCH) LOAD_REGS(k0 + (c + 1) * BK)

        {
            const int ib0 = kl * 256 + wv * 64 + ln;
            const bf16x8 bh0 = __builtin_bit_cast(bf16x8, *(const short8*)&Bh[ib0 * 8]);
            const bf16x8 bm0 = __builtin_bit_cast(bf16x8, *(const short8*)&Bm_[ib0 * 8]);
            const bf16x8 bl0 = __builtin_bit_cast(bf16x8, *(const short8*)&Bl[ib0 * 8]);
            const bf16x8 bh1 = __builtin_bit_cast(bf16x8, *(const short8*)&Bh[(ib0 + 32) * 8]);
            const bf16x8 bm1 = __builtin_bit_cast(bf16x8, *(const short8*)&Bm_[(ib0 + 32) * 8]);
            const bf16x8 bl1 = __builtin_bit_cast(bf16x8, *(const short8*)&Bl[(ib0 + 32) * 8]);
#pragma unroll
            for (int rt = 0; rt < 4; ++rt) {
                const int ia = kl * 128 + ((rt * 32 + ln) ^ kl);
                const bf16x8 ah = __builtin_bit_cast(bf16x8, *(const short8*)&Ah[ia * 8]);
                const bf16x8 aM = __builtin_bit_cast(bf16x8, *(const short8*)&Am_[ia * 8]);
                const bf16x8 aL = __builtin_bit_cast(bf16x8, *(const short8*)&Al[ia * 8]);
                acc[rt*2+0] = MFMA(ah, bh0, acc[rt*2+0]);
                acc[rt*2+0] = MFMA(ah, bm0, acc[rt*2+0]);
                acc[rt*2+0] = MFMA(aM, bh0, acc[rt*2+0]);
                acc[rt*2+0] = MFMA(aM, bm0, acc[rt*2+0]);
                acc[rt*2+0] = MFMA(ah, bl0, acc[rt*2+0]);
                acc[rt*2+0] = MFMA(aL, bh0, acc[rt*2+0]);
                acc[rt*2+1] = MFMA(ah, bh1, acc[rt*2+1]);
                acc[rt*2+1] = MFMA(ah, bm1, acc[rt*2+1]);
                acc[rt*2+1] = MFMA(aM, bh1, acc[rt*2+1]);
                acc[rt*2+1] = MFMA(aM, bm1, acc[rt*2+1]);
                acc[rt*2+1] = MFMA(ah, bl1, acc[rt*2+1]);
                acc[rt*2+1] = MFMA(aL, bh1, acc[rt*2+1]);
            }
        }

        if (c + 1 < NCH) {
            __syncthreads();
            SPLIT_STORE()
            __syncthreads();
        }
    }
#undef LOAD_REGS
#undef SPLIT_STORE

    // Epilogue: C/D layout (verified m74/m101): col = ln, row = (r&3)+8*(r>>2)+4*kl
    float* P = part + ((size_t)s * B_ + b0) * H_;
#pragma unroll
    for (int rt = 0; rt < 4; ++rt) {
#pragma unroll
        for (int ctl = 0; ctl < 2; ++ctl) {
            const f32x16 v = acc[rt * 2 + ctl];
            const int col = wv * 64 + ctl * 32 + ln;
#pragma unroll
            for (int r = 0; r < 16; ++r) {
                const int row = rt * 32 + (r & 3) + 8 * (r >> 2) + 4 * kl;
                P[(size_t)row * H_ + col] = v[r];
            }
        }
    }
}

// ---------------------------------------------------------------------------
// Gate: one wave per row. x = sum(partials)+b1 (coalesced float4), exact GELU,
// logits via W2, 64-lane butterfly reduce, top-2 softmax, dense w + sel/wt.
// ---------------------------------------------------------------------------
__device__ __forceinline__ float gelu_exact(float x) {
    return 0.5f * x * (1.0f + erff(x * 0.70710678118654752f));
}

__global__ __launch_bounds__(256)
void gate_kernel(const float* __restrict__ part, const float* __restrict__ b1,
                 const float* __restrict__ W2, const float* __restrict__ b2,
                 float* __restrict__ w_out, int2* __restrict__ sel,
                 float2* __restrict__ wt)
{
    const int t    = threadIdx.x;
    const int wv   = t >> 6;
    const int lane = t & 63;
    const int row  = blockIdx.x * 4 + wv;

    const float* pr = part + (size_t)row * H_ + lane * 4;
    float4 x = *(const float4*)pr;
    const float4 x1 = *(const float4*)(pr + (size_t)B_ * H_);
    const float4 x2 = *(const float4*)(pr + (size_t)2 * B_ * H_);
    const float4 x3 = *(const float4*)(pr + (size_t)3 * B_ * H_);
    const float4 bb = *(const float4*)&b1[lane * 4];
    const float h0 = gelu_exact(x.x + x1.x + x2.x + x3.x + bb.x);
    const float h1 = gelu_exact(x.y + x1.y + x2.y + x3.y + bb.y);
    const float h2 = gelu_exact(x.z + x1.z + x2.z + x3.z + bb.z);
    const float h3 = gelu_exact(x.w + x1.w + x2.w + x3.w + bb.w);

    float lg[8] = {0, 0, 0, 0, 0, 0, 0, 0};
    const int cb = lane * 4;
#define ACC8(HC, CI) {                                                         \
    const float4 wa_ = *(const float4*)&W2[(cb + (CI)) * 8];                   \
    const float4 wb_ = *(const float4*)&W2[(cb + (CI)) * 8 + 4];               \
    lg[0] = fmaf((HC), wa_.x, lg[0]); lg[1] = fmaf((HC), wa_.y, lg[1]);        \
    lg[2] = fmaf((HC), wa_.z, lg[2]); lg[3] = fmaf((HC), wa_.w, lg[3]);        \
    lg[4] = fmaf((HC), wb_.x, lg[4]); lg[5] = fmaf((HC), wb_.y, lg[5]);        \
    lg[6] = fmaf((HC), wb_.z, lg[6]); lg[7] = fmaf((HC), wb_.w, lg[7]);        \
}
    ACC8(h0, 0) ACC8(h1, 1) ACC8(h2, 2) ACC8(h3, 3)
#undef ACC8

#pragma unroll
    for (int off = 32; off >= 1; off >>= 1) {
#pragma unroll
        for (int i = 0; i < 8; ++i) lg[i] += __shfl_xor(lg[i], off, 64);
    }

    if (lane == 0) {
        float l[8];
#pragma unroll
        for (int i = 0; i < 8; ++i) l[i] = lg[i] + b2[i];
        int i1 = 0; float l1 = l[0];
#pragma unroll
        for (int i = 1; i < 8; ++i) if (l[i] > l1) { l1 = l[i]; i1 = i; }
        int i2 = (i1 == 0) ? 1 : 0; float l2 = l[i2];
#pragma unroll
        for (int i = 0; i < 8; ++i)
            if (i != i1 && l[i] > l2) { l2 = l[i]; i2 = i; }

        const float e  = expf(l2 - l1);
        const float dn = 1.0f + e;
        const float wa = 1.0f / dn;
        const float wb = e / dn;

        float* wr = w_out + (size_t)row * M_;
#pragma unroll
        for (int i = 0; i < 8; ++i)
            wr[i] = (i == i1) ? wa : ((i == i2) ? wb : 0.0f);
        sel[row] = make_int2(i1, i2);
        wt[row]  = make_float2(wa, wb);
    }
}

// ---------------------------------------------------------------------------
// Combine: fused[b,:] = wa*zs[e1,b,:] + wb*zs[e2,b,:]
// ---------------------------------------------------------------------------
__global__ __launch_bounds__(256)
void combine_kernel(const float* __restrict__ zs, const int2* __restrict__ sel,
                    const float2* __restrict__ wt, float* __restrict__ fused)
{
    const int b = blockIdx.x;
    const int2   e = sel[b];
    const float2 w = wt[b];
    const float4* z1 = (const float4*)(zs + ((size_t)e.x * B_ + b) * D_);
    const float4* z2 = (const float4*)(zs + ((size_t)e.y * B_ + b) * D_);
    float4* o = (float4*)(fused + (size_t)b * D_);
    const int d = threadIdx.x;
    const float4 x = z1[d];
    const float4 y = z2[d];
    o[d] = make_float4(fmaf(w.x, x.x, w.y * y.x),
                       fmaf(w.x, x.y, w.y * y.y),
                       fmaf(w.x, x.z, w.y * y.z),
                       fmaf(w.x, x.w, w.y * y.w));
}

// ---------------------------------------------------------------------------
extern "C" void kernel_launch(void* const* d_in, const int* in_sizes, int n_in,
                              void* d_out, int out_size, void* d_ws, size_t ws_size,
                              hipStream_t stream)
{
    const float* zs = (const float*)d_in[0];
    const float* W1 = (const float*)d_in[1];
    const float* b1 = (const float*)d_in[2];
    const float* W2 = (const float*)d_in[3];
    const float* b2 = (const float*)d_in[4];

    float* fused = (float*)d_out;                    // [8192][1024]
    float* w_out = fused + (size_t)B_ * D_;          // [8192][8]

    // ws: part [4][8192][256] fp32 (32 MB) | sel int2[B] | wt float2[B]
    float*  part = (float*)d_ws;
    int2*   sel  = (int2*)(part + (size_t)SPLITK * B_ * H_);
    float2* wt   = (float2*)(sel + B_);

    gemm1_kernel<<<dim3(B_ / BM, SPLITK), 256, 0, stream>>>(zs, W1, part);
    gate_kernel<<<dim3(B_ / 4), 256, 0, stream>>>(part, b1, W2, b2, w_out, sel, wt);
    combine_kernel<<<dim3(B_), 256, 0, stream>>>(zs, sel, wt, fused);
}